// Round 1
// baseline (76655.029 us; speedup 1.0000x reference)
//
#include <hip/hip_runtime.h>
#include <math.h>

#define T_SEQ 4096
#define H_DIM 1024
#define G4    4096
#define NBLK  256
#define CNT_STRIDE 32   // pad counters to 128B lines

// ---------------------------------------------------------------------------
// K1: xg[t][j] = dot(embedding[tokens[t]], w_ih[j]) + b_ih[j] + b_hh[j]
// fp32 GEMM, 128x128 tile, BK=16, 256 threads, 8x8 microtile.
// ---------------------------------------------------------------------------
__global__ __launch_bounds__(256) void xg_gemm(
    const int* __restrict__ tokens, const float* __restrict__ emb,
    const float* __restrict__ w_ih, const float* __restrict__ b_ih,
    const float* __restrict__ b_hh, float* __restrict__ xg)
{
    __shared__ float As[16][128];
    __shared__ float Bs[16][128];
    __shared__ int   tk[128];

    const int tid  = threadIdx.x;
    const int row0 = blockIdx.y * 128;
    const int col0 = blockIdx.x * 128;

    if (tid < 128) tk[tid] = tokens[row0 + tid];
    __syncthreads();

    const int r    = tid >> 1;      // staging row 0..127
    const int half = tid & 1;       // staging k-half
    const int tx   = tid & 15;
    const int ty   = tid >> 4;

    const float* ap_base = emb + (size_t)tk[r] * 1024 + half * 8;
    const float* bp_base = w_ih + (size_t)(col0 + r) * 1024 + half * 8;

    float acc[8][8] = {};

    for (int kc = 0; kc < 1024; kc += 16) {
        const float4 a0 = ((const float4*)(ap_base + kc))[0];
        const float4 a1 = ((const float4*)(ap_base + kc))[1];
        const float4 b0 = ((const float4*)(bp_base + kc))[0];
        const float4 b1 = ((const float4*)(bp_base + kc))[1];
        __syncthreads();   // previous compute finished before overwrite
        const int kb = half * 8;
        As[kb+0][r] = a0.x; As[kb+1][r] = a0.y; As[kb+2][r] = a0.z; As[kb+3][r] = a0.w;
        As[kb+4][r] = a1.x; As[kb+5][r] = a1.y; As[kb+6][r] = a1.z; As[kb+7][r] = a1.w;
        Bs[kb+0][r] = b0.x; Bs[kb+1][r] = b0.y; Bs[kb+2][r] = b0.z; Bs[kb+3][r] = b0.w;
        Bs[kb+4][r] = b1.x; Bs[kb+5][r] = b1.y; Bs[kb+6][r] = b1.z; Bs[kb+7][r] = b1.w;
        __syncthreads();
        #pragma unroll
        for (int k = 0; k < 16; ++k) {
            const float4 a0v = *(const float4*)&As[k][ty*8];
            const float4 a1v = *(const float4*)&As[k][ty*8+4];
            const float4 b0v = *(const float4*)&Bs[k][tx*8];
            const float4 b1v = *(const float4*)&Bs[k][tx*8+4];
            const float aa[8] = {a0v.x,a0v.y,a0v.z,a0v.w,a1v.x,a1v.y,a1v.z,a1v.w};
            const float bb[8] = {b0v.x,b0v.y,b0v.z,b0v.w,b1v.x,b1v.y,b1v.z,b1v.w};
            #pragma unroll
            for (int ii = 0; ii < 8; ++ii)
                #pragma unroll
                for (int jj = 0; jj < 8; ++jj)
                    acc[ii][jj] = fmaf(aa[ii], bb[jj], acc[ii][jj]);
        }
    }

    // epilogue: add (b_ih + b_hh) and store
    const int ccol = col0 + tx * 8;
    float bs[8];
    #pragma unroll
    for (int jj = 0; jj < 8; ++jj) bs[jj] = b_ih[ccol + jj] + b_hh[ccol + jj];
    #pragma unroll
    for (int ii = 0; ii < 8; ++ii) {
        float* orow = xg + (size_t)(row0 + ty*8 + ii) * G4 + ccol;
        float4 o0, o1;
        o0.x = acc[ii][0] + bs[0]; o0.y = acc[ii][1] + bs[1];
        o0.z = acc[ii][2] + bs[2]; o0.w = acc[ii][3] + bs[3];
        o1.x = acc[ii][4] + bs[4]; o1.y = acc[ii][5] + bs[5];
        o1.z = acc[ii][6] + bs[6]; o1.w = acc[ii][7] + bs[7];
        ((float4*)orow)[0] = o0;
        ((float4*)orow)[1] = o1;
    }
}

// ---------------------------------------------------------------------------
// K2: persistent LSTM scan. 256 blocks x 256 threads. Block b owns
// k-lanes {4b..4b+3}; wave w (= gate) computes rows w*1024 + 4b + m.
// w_hh slice lives in VGPRs (16 float4/thread). h broadcast via 2-slot
// global ring + per-step release/acquire counters.
// ---------------------------------------------------------------------------
__device__ __forceinline__ float sigmoidf_(float x) {
    return 1.0f / (1.0f + expf(-x));
}

__global__ __launch_bounds__(256) void lstm_scan(
    const float* __restrict__ xg, const float* __restrict__ w_hh,
    const float* __restrict__ h0, const float* __restrict__ c0,
    float* __restrict__ h_ring, float* __restrict__ h_fin,
    float* __restrict__ c_fin, unsigned* __restrict__ cnt)
{
    __shared__ float h_lds[H_DIM];
    __shared__ float dot_lds[16];

    const int tid  = threadIdx.x;
    const int b    = blockIdx.x;
    const int w    = tid >> 6;       // wave index = gate index (i,f,g,o)
    const int lane = tid & 63;
    const int s    = lane >> 2;      // k-slice 0..15 (64 floats each)
    const int m    = lane & 3;       // which of the block's 4 h-lanes
    const int row  = w * 1024 + 4 * b + m;

    // resident weights, chunk order rotated by s to kill LDS bank conflicts
    float4 wf[16];
    {
        const float* wp = w_hh + (size_t)row * 1024 + 64 * s;
        #pragma unroll
        for (int i = 0; i < 16; ++i) {
            const int c = (i + s) & 15;
            wf[i] = *(const float4*)(wp + 4 * c);
        }
    }

    float c_reg = 0.0f;
    if (tid < 4) c_reg = c0[4 * b + tid];

    for (int t = 0; t < T_SEQ; ++t) {
        // prefetch this step's input-side gate values (hidden under the spin)
        float xv0 = 0.f, xv1 = 0.f, xv2 = 0.f, xv3 = 0.f;
        if (tid < 4) {
            const float* p = xg + (size_t)t * G4 + 4 * b + tid;
            xv0 = p[0]; xv1 = p[1024]; xv2 = p[2048]; xv3 = p[3072];
        }

        // wait for h[t-1] to be fully published
        if (t > 0) {
            if (tid == 0) {
                const unsigned* a = &cnt[(size_t)(t - 1) * CNT_STRIDE];
                while (__hip_atomic_load(a, __ATOMIC_RELAXED,
                                         __HIP_MEMORY_SCOPE_AGENT) != NBLK) { }
            }
            __syncthreads();                                  // (A)
            __builtin_amdgcn_fence(__ATOMIC_ACQUIRE, "agent"); // inv stale L1/L2
        }

        // stage h into LDS (4 floats per thread)
        const float* hsrc = (t == 0) ? h0 : (h_ring + ((t - 1) & 1) * H_DIM);
        const float4 hv = ((const float4*)hsrc)[tid];
        ((float4*)h_lds)[tid] = hv;
        __syncthreads();                                      // (C)

        // 64-MAC partial dot from resident weights + broadcast h
        float acc = 0.0f;
        const float4* h4 = (const float4*)h_lds;
        #pragma unroll
        for (int i = 0; i < 16; ++i) {
            const int c = (i + s) & 15;
            const float4 x = h4[16 * s + c];
            acc += wf[i].x * x.x + wf[i].y * x.y + wf[i].z * x.z + wf[i].w * x.w;
        }
        // reduce over the 16 slices (lanes stride 4)
        acc += __shfl_xor(acc, 4);
        acc += __shfl_xor(acc, 8);
        acc += __shfl_xor(acc, 16);
        acc += __shfl_xor(acc, 32);
        if (lane < 4) dot_lds[w * 4 + lane] = acc;
        __syncthreads();                                      // (B)

        // pointwise LSTM update for the block's 4 h-lanes
        if (tid < 4) {
            const float gi = xv0 + dot_lds[0  + tid];
            const float gf = xv1 + dot_lds[4  + tid];
            const float gg = xv2 + dot_lds[8  + tid];
            const float go = xv3 + dot_lds[12 + tid];
            const float ii = sigmoidf_(gi);
            const float ff = sigmoidf_(gf);
            const float gt = tanhf(gg);
            const float oo = sigmoidf_(go);
            c_reg = ff * c_reg + ii * gt;
            const float hn = oo * tanhf(c_reg);
            h_ring[(t & 1) * H_DIM + 4 * b + tid] = hn;
            if (t == T_SEQ - 1) {
                h_fin[4 * b + tid] = hn;
                c_fin[4 * b + tid] = c_reg;
            }
            if (tid == 0) {
                __hip_atomic_fetch_add(&cnt[(size_t)t * CNT_STRIDE], 1u,
                                       __ATOMIC_RELEASE, __HIP_MEMORY_SCOPE_AGENT);
            }
        }
    }
}

// ---------------------------------------------------------------------------
// K3: four 256x1024 mat-vec projections + bias.  One output per 32-lane group.
// ---------------------------------------------------------------------------
__global__ __launch_bounds__(256) void proj_kernel(
    const float* __restrict__ h_fin, const float* __restrict__ c_fin,
    const float* __restrict__ W_hm, const float* __restrict__ b_hm,
    const float* __restrict__ W_hv, const float* __restrict__ b_hv,
    const float* __restrict__ W_cm, const float* __restrict__ b_cm,
    const float* __restrict__ W_cv, const float* __restrict__ b_cv,
    float* __restrict__ out)
{
    const int tid = threadIdx.x;
    const int g32 = tid >> 5;
    const int j   = tid & 31;
    const int o   = blockIdx.x * 8 + g32;   // 0..1023
    const int mat = o >> 8;
    const int l   = o & 255;

    const float* W;  const float* bias;  const float* vec;
    if      (mat == 0) { W = W_hm; bias = b_hm; vec = h_fin; }
    else if (mat == 1) { W = W_hv; bias = b_hv; vec = h_fin; }
    else if (mat == 2) { W = W_cm; bias = b_cm; vec = c_fin; }
    else               { W = W_cv; bias = b_cv; vec = c_fin; }

    const float* wrow = W + (size_t)l * 1024;
    float acc = 0.0f;
    #pragma unroll
    for (int i = 0; i < 8; ++i) {
        const float4 wv = *(const float4*)(wrow + i * 128 + j * 4);
        const float4 xv = *(const float4*)(vec  + i * 128 + j * 4);
        acc += wv.x * xv.x + wv.y * xv.y + wv.z * xv.z + wv.w * xv.w;
    }
    acc += __shfl_xor(acc, 1);
    acc += __shfl_xor(acc, 2);
    acc += __shfl_xor(acc, 4);
    acc += __shfl_xor(acc, 8);
    acc += __shfl_xor(acc, 16);
    if (j == 0) out[o] = acc + bias[l];
}

// ---------------------------------------------------------------------------
extern "C" void kernel_launch(void* const* d_in, const int* in_sizes, int n_in,
                              void* d_out, int out_size, void* d_ws, size_t ws_size,
                              hipStream_t stream)
{
    const int*   tokens = (const int*)  d_in[0];
    const float* h0     = (const float*)d_in[1];
    const float* c0     = (const float*)d_in[2];
    const float* emb    = (const float*)d_in[3];
    const float* w_ih   = (const float*)d_in[4];
    const float* w_hh   = (const float*)d_in[5];
    const float* b_ih   = (const float*)d_in[6];
    const float* b_hh   = (const float*)d_in[7];
    const float* W_hm   = (const float*)d_in[8];
    const float* b_hm   = (const float*)d_in[9];
    const float* W_hv   = (const float*)d_in[10];
    const float* b_hv   = (const float*)d_in[11];
    const float* W_cm   = (const float*)d_in[12];
    const float* b_cm   = (const float*)d_in[13];
    const float* W_cv   = (const float*)d_in[14];
    const float* b_cv   = (const float*)d_in[15];
    float* out = (float*)d_out;

    char* ws = (char*)d_ws;
    float*    xg     = (float*)ws;                     // T*4H fp32 = 64 MB
    size_t    off    = (size_t)T_SEQ * G4 * sizeof(float);
    float*    h_ring = (float*)(ws + off); off += 2 * H_DIM * sizeof(float);
    float*    h_fin  = (float*)(ws + off); off += H_DIM * sizeof(float);
    float*    c_fin  = (float*)(ws + off); off += H_DIM * sizeof(float);
    unsigned* cnt    = (unsigned*)(ws + off);
    const size_t cnt_bytes = (size_t)T_SEQ * CNT_STRIDE * sizeof(unsigned);

    hipMemsetAsync(cnt, 0, cnt_bytes, stream);
    xg_gemm<<<dim3(32, 32), 256, 0, stream>>>(tokens, emb, w_ih, b_ih, b_hh, xg);
    lstm_scan<<<NBLK, 256, 0, stream>>>(xg, w_hh, h0, c0, h_ring, h_fin, c_fin, cnt);
    proj_kernel<<<128, 256, 0, stream>>>(h_fin, c_fin, W_hm, b_hm, W_hv, b_hv,
                                         W_cm, b_cm, W_cv, b_cv, out);
}

// Round 2
// 13114.165 us; speedup vs baseline: 5.8452x; 5.8452x over previous
//
#include <hip/hip_runtime.h>
#include <math.h>

#define T_SEQ 4096
#define H_DIM 1024
#define G4    4096
#define NBLK  256

// ---------------------------------------------------------------------------
// K1: xg[t][j] = dot(embedding[tokens[t]], w_ih[j]) + b_ih[j] + b_hh[j]
// fp32 GEMM, 128x128 tile, BK=16, 256 threads, 8x8 microtile.
// ---------------------------------------------------------------------------
__global__ __launch_bounds__(256) void xg_gemm(
    const int* __restrict__ tokens, const float* __restrict__ emb,
    const float* __restrict__ w_ih, const float* __restrict__ b_ih,
    const float* __restrict__ b_hh, float* __restrict__ xg)
{
    __shared__ float As[16][128];
    __shared__ float Bs[16][128];
    __shared__ int   tk[128];

    const int tid  = threadIdx.x;
    const int row0 = blockIdx.y * 128;
    const int col0 = blockIdx.x * 128;

    if (tid < 128) tk[tid] = tokens[row0 + tid];
    __syncthreads();

    const int r    = tid >> 1;      // staging row 0..127
    const int half = tid & 1;       // staging k-half
    const int tx   = tid & 15;
    const int ty   = tid >> 4;

    const float* ap_base = emb + (size_t)tk[r] * 1024 + half * 8;
    const float* bp_base = w_ih + (size_t)(col0 + r) * 1024 + half * 8;

    float acc[8][8] = {};

    for (int kc = 0; kc < 1024; kc += 16) {
        const float4 a0 = ((const float4*)(ap_base + kc))[0];
        const float4 a1 = ((const float4*)(ap_base + kc))[1];
        const float4 b0 = ((const float4*)(bp_base + kc))[0];
        const float4 b1 = ((const float4*)(bp_base + kc))[1];
        __syncthreads();   // previous compute finished before overwrite
        const int kb = half * 8;
        As[kb+0][r] = a0.x; As[kb+1][r] = a0.y; As[kb+2][r] = a0.z; As[kb+3][r] = a0.w;
        As[kb+4][r] = a1.x; As[kb+5][r] = a1.y; As[kb+6][r] = a1.z; As[kb+7][r] = a1.w;
        Bs[kb+0][r] = b0.x; Bs[kb+1][r] = b0.y; Bs[kb+2][r] = b0.z; Bs[kb+3][r] = b0.w;
        Bs[kb+4][r] = b1.x; Bs[kb+5][r] = b1.y; Bs[kb+6][r] = b1.z; Bs[kb+7][r] = b1.w;
        __syncthreads();
        #pragma unroll
        for (int k = 0; k < 16; ++k) {
            const float4 a0v = *(const float4*)&As[k][ty*8];
            const float4 a1v = *(const float4*)&As[k][ty*8+4];
            const float4 b0v = *(const float4*)&Bs[k][tx*8];
            const float4 b1v = *(const float4*)&Bs[k][tx*8+4];
            const float aa[8] = {a0v.x,a0v.y,a0v.z,a0v.w,a1v.x,a1v.y,a1v.z,a1v.w};
            const float bb[8] = {b0v.x,b0v.y,b0v.z,b0v.w,b1v.x,b1v.y,b1v.z,b1v.w};
            #pragma unroll
            for (int ii = 0; ii < 8; ++ii)
                #pragma unroll
                for (int jj = 0; jj < 8; ++jj)
                    acc[ii][jj] = fmaf(aa[ii], bb[jj], acc[ii][jj]);
        }
    }

    const int ccol = col0 + tx * 8;
    float bs[8];
    #pragma unroll
    for (int jj = 0; jj < 8; ++jj) bs[jj] = b_ih[ccol + jj] + b_hh[ccol + jj];
    #pragma unroll
    for (int ii = 0; ii < 8; ++ii) {
        float* orow = xg + (size_t)(row0 + ty*8 + ii) * G4 + ccol;
        float4 o0, o1;
        o0.x = acc[ii][0] + bs[0]; o0.y = acc[ii][1] + bs[1];
        o0.z = acc[ii][2] + bs[2]; o0.w = acc[ii][3] + bs[3];
        o1.x = acc[ii][4] + bs[4]; o1.y = acc[ii][5] + bs[5];
        o1.z = acc[ii][6] + bs[6]; o1.w = acc[ii][7] + bs[7];
        ((float4*)orow)[0] = o0;
        ((float4*)orow)[1] = o1;
    }
}

// ---------------------------------------------------------------------------
// K2: persistent LSTM scan.  256 blocks x 256 threads; block b owns h-lanes
// {4b..4b+3} (16 gate rows).  w_hh slice pinned in VGPRs (16 float4/thread).
// Cross-block h exchange: one 8-byte agent-scope atomic per value, carrying
// {tag = step version (hi 32), float bits (lo 32)}.  No fences, no shared
// counters, no release/acquire — tag travels atomically with the data, so a
// single one-way L3 trip synchronizes each step.  2-slot ring is safe since
// max inter-block skew is 1 step (a block can't pass step t without all of
// step t-1's data).
// ---------------------------------------------------------------------------
__device__ __forceinline__ float sigmoidf_(float x) {
    return 1.0f / (1.0f + expf(-x));
}

__global__ __launch_bounds__(256) void lstm_scan(
    const float* __restrict__ xg, const float* __restrict__ w_hh,
    const float* __restrict__ h0, const float* __restrict__ c0,
    unsigned long long* h_msg,           // [2][1024] {tag,bits}
    float* __restrict__ h_fin, float* __restrict__ c_fin)
{
    __shared__ float h_lds[H_DIM];
    __shared__ float dot_lds[16];

    const int tid  = threadIdx.x;
    const int b    = blockIdx.x;
    const int w    = tid >> 6;       // wave index = gate index (i,f,g,o)
    const int lane = tid & 63;
    const int s    = lane >> 2;      // k-slice 0..15 (64 floats each)
    const int m    = lane & 3;       // which of the block's 4 h-lanes
    const int row  = w * 1024 + 4 * b + m;

    // resident weights; chunk order rotated by s so the h_lds reads that pair
    // with them are bank-conflict-free
    float4 wf[16];
    {
        const float* wp = w_hh + (size_t)row * 1024 + 64 * s;
        #pragma unroll
        for (int i = 0; i < 16; ++i) {
            const int c = (i + s) & 15;
            wf[i] = *(const float4*)(wp + 4 * c);
        }
    }
    // pin: opaque-modify each element so the compiler can't re-load from
    // global inside the t-loop (round-1 showed it sinking these loads:
    // VGPR_Count=60, FETCH_SIZE 360MB)
    #pragma unroll
    for (int i = 0; i < 16; ++i)
        asm volatile("" : "+v"(wf[i].x), "+v"(wf[i].y), "+v"(wf[i].z), "+v"(wf[i].w));

    float c_reg = 0.0f;
    if (tid < 4) c_reg = c0[4 * b + tid];

    // version 0 of h comes straight from h0
    ((float4*)h_lds)[tid] = ((const float4*)h0)[tid];
    __syncthreads();

    for (int t = 0; t < T_SEQ; ++t) {
        // prefetch this step's input-side gate values
        float xv0 = 0.f, xv1 = 0.f, xv2 = 0.f, xv3 = 0.f;
        if (tid < 4) {
            const float* p = xg + (size_t)t * G4 + 4 * b + tid;
            xv0 = p[0]; xv1 = p[1024]; xv2 = p[2048]; xv3 = p[3072];
        }

        // 64-MAC partial dot: resident weights x broadcast h (LDS)
        float acc = 0.0f;
        const float4* h4 = (const float4*)h_lds;
        #pragma unroll
        for (int i = 0; i < 16; ++i) {
            const int c = (i + s) & 15;
            const float4 x = h4[16 * s + c];
            acc = fmaf(wf[i].x, x.x, acc);
            acc = fmaf(wf[i].y, x.y, acc);
            acc = fmaf(wf[i].z, x.z, acc);
            acc = fmaf(wf[i].w, x.w, acc);
        }
        acc += __shfl_xor(acc, 4);
        acc += __shfl_xor(acc, 8);
        acc += __shfl_xor(acc, 16);
        acc += __shfl_xor(acc, 32);
        if (lane < 4) dot_lds[w * 4 + lane] = acc;
        __syncthreads();

        // pointwise update + publish (as early as possible)
        if (tid < 4) {
            const float gi = xv0 + dot_lds[0  + tid];
            const float gf = xv1 + dot_lds[4  + tid];
            const float gg = xv2 + dot_lds[8  + tid];
            const float go = xv3 + dot_lds[12 + tid];
            const float ii = sigmoidf_(gi);
            const float ff = sigmoidf_(gf);
            const float gt = tanhf(gg);
            const float oo = sigmoidf_(go);
            c_reg = ff * c_reg + ii * gt;
            const float hn = oo * tanhf(c_reg);
            const unsigned long long msg =
                ((unsigned long long)(unsigned)(t + 1) << 32) | __float_as_uint(hn);
            __hip_atomic_store(&h_msg[(size_t)((t + 1) & 1) * H_DIM + 4 * b + tid],
                               msg, __ATOMIC_RELAXED, __HIP_MEMORY_SCOPE_AGENT);
            if (t == T_SEQ - 1) {
                h_fin[4 * b + tid] = hn;
                c_fin[4 * b + tid] = c_reg;
            }
        }

        // gather h version t+1 (each thread owns 4 consecutive h values)
        if (t < T_SEQ - 1) {
            const unsigned ver = (unsigned)(t + 1);
            const unsigned long long* src =
                h_msg + (size_t)(ver & 1) * H_DIM + 4 * tid;
            unsigned long long v0, v1, v2, v3;
            for (;;) {
                v0 = __hip_atomic_load(src + 0, __ATOMIC_RELAXED, __HIP_MEMORY_SCOPE_AGENT);
                v1 = __hip_atomic_load(src + 1, __ATOMIC_RELAXED, __HIP_MEMORY_SCOPE_AGENT);
                v2 = __hip_atomic_load(src + 2, __ATOMIC_RELAXED, __HIP_MEMORY_SCOPE_AGENT);
                v3 = __hip_atomic_load(src + 3, __ATOMIC_RELAXED, __HIP_MEMORY_SCOPE_AGENT);
                if (((unsigned)(v0 >> 32) == ver) & ((unsigned)(v1 >> 32) == ver) &
                    ((unsigned)(v2 >> 32) == ver) & ((unsigned)(v3 >> 32) == ver))
                    break;
            }
            float4 hv;
            hv.x = __uint_as_float((unsigned)v0);
            hv.y = __uint_as_float((unsigned)v1);
            hv.z = __uint_as_float((unsigned)v2);
            hv.w = __uint_as_float((unsigned)v3);
            ((float4*)h_lds)[tid] = hv;
            __syncthreads();
        }
    }
}

// ---------------------------------------------------------------------------
// K3: four 256x1024 mat-vec projections + bias.  One output per 32-lane group.
// ---------------------------------------------------------------------------
__global__ __launch_bounds__(256) void proj_kernel(
    const float* __restrict__ h_fin, const float* __restrict__ c_fin,
    const float* __restrict__ W_hm, const float* __restrict__ b_hm,
    const float* __restrict__ W_hv, const float* __restrict__ b_hv,
    const float* __restrict__ W_cm, const float* __restrict__ b_cm,
    const float* __restrict__ W_cv, const float* __restrict__ b_cv,
    float* __restrict__ out)
{
    const int tid = threadIdx.x;
    const int g32 = tid >> 5;
    const int j   = tid & 31;
    const int o   = blockIdx.x * 8 + g32;   // 0..1023
    const int mat = o >> 8;
    const int l   = o & 255;

    const float* W;  const float* bias;  const float* vec;
    if      (mat == 0) { W = W_hm; bias = b_hm; vec = h_fin; }
    else if (mat == 1) { W = W_hv; bias = b_hv; vec = h_fin; }
    else if (mat == 2) { W = W_cm; bias = b_cm; vec = c_fin; }
    else               { W = W_cv; bias = b_cv; vec = c_fin; }

    const float* wrow = W + (size_t)l * 1024;
    float acc = 0.0f;
    #pragma unroll
    for (int i = 0; i < 8; ++i) {
        const float4 wv = *(const float4*)(wrow + i * 128 + j * 4);
        const float4 xv = *(const float4*)(vec  + i * 128 + j * 4);
        acc += wv.x * xv.x + wv.y * xv.y + wv.z * xv.z + wv.w * xv.w;
    }
    acc += __shfl_xor(acc, 1);
    acc += __shfl_xor(acc, 2);
    acc += __shfl_xor(acc, 4);
    acc += __shfl_xor(acc, 8);
    acc += __shfl_xor(acc, 16);
    if (j == 0) out[o] = acc + bias[l];
}

// ---------------------------------------------------------------------------
extern "C" void kernel_launch(void* const* d_in, const int* in_sizes, int n_in,
                              void* d_out, int out_size, void* d_ws, size_t ws_size,
                              hipStream_t stream)
{
    const int*   tokens = (const int*)  d_in[0];
    const float* h0     = (const float*)d_in[1];
    const float* c0     = (const float*)d_in[2];
    const float* emb    = (const float*)d_in[3];
    const float* w_ih   = (const float*)d_in[4];
    const float* w_hh   = (const float*)d_in[5];
    const float* b_ih   = (const float*)d_in[6];
    const float* b_hh   = (const float*)d_in[7];
    const float* W_hm   = (const float*)d_in[8];
    const float* b_hm   = (const float*)d_in[9];
    const float* W_hv   = (const float*)d_in[10];
    const float* b_hv   = (const float*)d_in[11];
    const float* W_cm   = (const float*)d_in[12];
    const float* b_cm   = (const float*)d_in[13];
    const float* W_cv   = (const float*)d_in[14];
    const float* b_cv   = (const float*)d_in[15];
    float* out = (float*)d_out;

    char* ws = (char*)d_ws;
    float*              xg    = (float*)ws;            // T*4H fp32 = 64 MB
    size_t              off   = (size_t)T_SEQ * G4 * sizeof(float);
    unsigned long long* h_msg = (unsigned long long*)(ws + off);
    off += 2 * H_DIM * sizeof(unsigned long long);     // 16 KB
    float* h_fin = (float*)(ws + off); off += H_DIM * sizeof(float);
    float* c_fin = (float*)(ws + off); off += H_DIM * sizeof(float);

    // clear stale tags (cheap; makes every replay wait for fresh data)
    hipMemsetAsync(h_msg, 0xFF, 2 * H_DIM * sizeof(unsigned long long), stream);

    xg_gemm<<<dim3(32, 32), 256, 0, stream>>>(tokens, emb, w_ih, b_ih, b_hh, xg);
    lstm_scan<<<NBLK, 256, 0, stream>>>(xg, w_hh, h0, c0, h_msg, h_fin, c_fin);
    proj_kernel<<<128, 256, 0, stream>>>(h_fin, c_fin, W_hm, b_hm, W_hv, b_hv,
                                         W_cm, b_cm, W_cv, b_cv, out);
}

// Round 3
// 13016.457 us; speedup vs baseline: 5.8891x; 1.0075x over previous
//
#include <hip/hip_runtime.h>
#include <math.h>

#define T_SEQ 4096
#define H_DIM 1024
#define G4    4096
#define NBLK  256

// ---------------------------------------------------------------------------
// K1: xg[t][j] = dot(embedding[tokens[t]], w_ih[j]) + b_ih[j] + b_hh[j]
// fp32 GEMM, 128x128 tile, BK=16, 256 threads, 8x8 microtile.
// ---------------------------------------------------------------------------
__global__ __launch_bounds__(256) void xg_gemm(
    const int* __restrict__ tokens, const float* __restrict__ emb,
    const float* __restrict__ w_ih, const float* __restrict__ b_ih,
    const float* __restrict__ b_hh, float* __restrict__ xg)
{
    __shared__ float As[16][128];
    __shared__ float Bs[16][128];
    __shared__ int   tk[128];

    const int tid  = threadIdx.x;
    const int row0 = blockIdx.y * 128;
    const int col0 = blockIdx.x * 128;

    if (tid < 128) tk[tid] = tokens[row0 + tid];
    __syncthreads();

    const int r    = tid >> 1;      // staging row 0..127
    const int half = tid & 1;       // staging k-half
    const int tx   = tid & 15;
    const int ty   = tid >> 4;

    const float* ap_base = emb + (size_t)tk[r] * 1024 + half * 8;
    const float* bp_base = w_ih + (size_t)(col0 + r) * 1024 + half * 8;

    float acc[8][8] = {};

    for (int kc = 0; kc < 1024; kc += 16) {
        const float4 a0 = ((const float4*)(ap_base + kc))[0];
        const float4 a1 = ((const float4*)(ap_base + kc))[1];
        const float4 b0 = ((const float4*)(bp_base + kc))[0];
        const float4 b1 = ((const float4*)(bp_base + kc))[1];
        __syncthreads();   // previous compute finished before overwrite
        const int kb = half * 8;
        As[kb+0][r] = a0.x; As[kb+1][r] = a0.y; As[kb+2][r] = a0.z; As[kb+3][r] = a0.w;
        As[kb+4][r] = a1.x; As[kb+5][r] = a1.y; As[kb+6][r] = a1.z; As[kb+7][r] = a1.w;
        Bs[kb+0][r] = b0.x; Bs[kb+1][r] = b0.y; Bs[kb+2][r] = b0.z; Bs[kb+3][r] = b0.w;
        Bs[kb+4][r] = b1.x; Bs[kb+5][r] = b1.y; Bs[kb+6][r] = b1.z; Bs[kb+7][r] = b1.w;
        __syncthreads();
        #pragma unroll
        for (int k = 0; k < 16; ++k) {
            const float4 a0v = *(const float4*)&As[k][ty*8];
            const float4 a1v = *(const float4*)&As[k][ty*8+4];
            const float4 b0v = *(const float4*)&Bs[k][tx*8];
            const float4 b1v = *(const float4*)&Bs[k][tx*8+4];
            const float aa[8] = {a0v.x,a0v.y,a0v.z,a0v.w,a1v.x,a1v.y,a1v.z,a1v.w};
            const float bb[8] = {b0v.x,b0v.y,b0v.z,b0v.w,b1v.x,b1v.y,b1v.z,b1v.w};
            #pragma unroll
            for (int ii = 0; ii < 8; ++ii)
                #pragma unroll
                for (int jj = 0; jj < 8; ++jj)
                    acc[ii][jj] = fmaf(aa[ii], bb[jj], acc[ii][jj]);
        }
    }

    const int ccol = col0 + tx * 8;
    float bs[8];
    #pragma unroll
    for (int jj = 0; jj < 8; ++jj) bs[jj] = b_ih[ccol + jj] + b_hh[ccol + jj];
    #pragma unroll
    for (int ii = 0; ii < 8; ++ii) {
        float* orow = xg + (size_t)(row0 + ty*8 + ii) * G4 + ccol;
        float4 o0, o1;
        o0.x = acc[ii][0] + bs[0]; o0.y = acc[ii][1] + bs[1];
        o0.z = acc[ii][2] + bs[2]; o0.w = acc[ii][3] + bs[3];
        o1.x = acc[ii][4] + bs[4]; o1.y = acc[ii][5] + bs[5];
        o1.z = acc[ii][6] + bs[6]; o1.w = acc[ii][7] + bs[7];
        ((float4*)orow)[0] = o0;
        ((float4*)orow)[1] = o1;
    }
}

// ---------------------------------------------------------------------------
// K2: persistent LSTM scan.  256 blocks x 256 threads; block b owns h-lanes
// {4b..4b+3} (16 gate rows).  w_hh slice pinned in VGPRs (16 float4/thread)
// via IN-LOOP asm pins (round-2 showed a pre-loop pin gets rematerialized:
// VGPR=60, FETCH 611MB).  Cross-block h exchange: 8-byte relaxed agent-scope
// atomics carrying {tag = version, float bits}; no fences, no counters.
// 2-slot ring safe: max inter-block skew is 1 step.
// ---------------------------------------------------------------------------
__device__ __forceinline__ float fsigmoid_(float x) {
    return 1.0f / (1.0f + __expf(-x));          // exp->inf => 0, no NaN
}
__device__ __forceinline__ float ftanh_(float x) {
    x = fminf(fmaxf(x, -10.0f), 10.0f);         // avoid inf/inf
    const float e = __expf(2.0f * x);
    return (e - 1.0f) / (e + 1.0f);
}

__global__ __launch_bounds__(256, 1) void lstm_scan(
    const float* __restrict__ xg, const float* __restrict__ w_hh,
    const float* __restrict__ h0, const float* __restrict__ c0,
    unsigned long long* h_msg,           // [2][1024] {tag,bits}
    float* __restrict__ h_fin, float* __restrict__ c_fin)
{
    __shared__ float h_lds[H_DIM];
    __shared__ float dot_lds[16];

    const int tid  = threadIdx.x;
    const int b    = blockIdx.x;
    const int w    = tid >> 6;       // wave index = gate index (i,f,g,o)
    const int lane = tid & 63;
    const int s    = lane >> 2;      // k-slice 0..15 (64 floats each)
    const int m    = lane & 3;       // which of the block's 4 h-lanes
    const int row  = w * 1024 + 4 * b + m;

    // resident weights; chunk order rotated by s so paired h_lds reads are
    // 2-way-bank at worst (free)
    float4 wf[16];
    {
        const float* wp = w_hh + (size_t)row * 1024 + 64 * s;
        #pragma unroll
        for (int i = 0; i < 16; ++i) {
            const int c = (i + s) & 15;
            wf[i] = *(const float4*)(wp + 4 * c);
        }
    }

    float c_reg = 0.0f;
    if (tid < 4) c_reg = c0[4 * b + tid];

    // version 0 of h comes straight from h0
    ((float4*)h_lds)[tid] = ((const float4*)h0)[tid];
    __syncthreads();

    // prefetch xg for t=0
    float xc0 = 0.f, xc1 = 0.f, xc2 = 0.f, xc3 = 0.f;
    if (tid < 4) {
        const float* p = xg + 4 * b + tid;
        xc0 = p[0]; xc1 = p[1024]; xc2 = p[2048]; xc3 = p[3072];
    }

    for (int t = 0; t < T_SEQ; ++t) {
        // ---- pin weights: loop-carried opaque dataflow => must stay in VGPRs
        #pragma unroll
        for (int i = 0; i < 16; ++i)
            asm volatile("" : "+v"(wf[i].x), "+v"(wf[i].y),
                              "+v"(wf[i].z), "+v"(wf[i].w));

        // issue next step's xg load now; consumed next iteration (latency
        // hidden under this step's dot + publish + poll)
        float xn0 = 0.f, xn1 = 0.f, xn2 = 0.f, xn3 = 0.f;
        if ((tid < 4) & (t < T_SEQ - 1)) {
            const float* p = xg + (size_t)(t + 1) * G4 + 4 * b + tid;
            xn0 = p[0]; xn1 = p[1024]; xn2 = p[2048]; xn3 = p[3072];
        }

        // 64-MAC partial dot: resident weights x broadcast h (LDS)
        float acc = 0.0f;
        const float4* h4 = (const float4*)h_lds;
        #pragma unroll
        for (int i = 0; i < 16; ++i) {
            const int c = (i + s) & 15;
            const float4 x = h4[16 * s + c];
            acc = fmaf(wf[i].x, x.x, acc);
            acc = fmaf(wf[i].y, x.y, acc);
            acc = fmaf(wf[i].z, x.z, acc);
            acc = fmaf(wf[i].w, x.w, acc);
        }
        acc += __shfl_xor(acc, 4);
        acc += __shfl_xor(acc, 8);
        acc += __shfl_xor(acc, 16);
        acc += __shfl_xor(acc, 32);
        if (lane < 4) dot_lds[w * 4 + lane] = acc;
        __syncthreads();

        // pointwise update + publish (4 threads; other waves fall through to
        // the poll below and spin concurrently)
        if (tid < 4) {
            const float gi = xc0 + dot_lds[0  + tid];
            const float gf = xc1 + dot_lds[4  + tid];
            const float gg = xc2 + dot_lds[8  + tid];
            const float go = xc3 + dot_lds[12 + tid];
            const float ii = fsigmoid_(gi);
            const float ff = fsigmoid_(gf);
            const float gt = ftanh_(gg);
            const float oo = fsigmoid_(go);
            c_reg = ff * c_reg + ii * gt;
            const float hn = oo * ftanh_(c_reg);
            const unsigned long long msg =
                ((unsigned long long)(unsigned)(t + 1) << 32) | __float_as_uint(hn);
            __hip_atomic_store(&h_msg[(size_t)((t + 1) & 1) * H_DIM + 4 * b + tid],
                               msg, __ATOMIC_RELAXED, __HIP_MEMORY_SCOPE_AGENT);
            if (t == T_SEQ - 1) {
                h_fin[4 * b + tid] = hn;
                c_fin[4 * b + tid] = c_reg;
            }
        }
        xc0 = xn0; xc1 = xn1; xc2 = xn2; xc3 = xn3;

        // gather h version t+1 (each thread owns 4 consecutive h values)
        if (t < T_SEQ - 1) {
            const unsigned ver = (unsigned)(t + 1);
            const unsigned long long* src =
                h_msg + (size_t)(ver & 1) * H_DIM + 4 * tid;
            unsigned long long v0, v1, v2, v3;
            for (;;) {
                v0 = __hip_atomic_load(src + 0, __ATOMIC_RELAXED, __HIP_MEMORY_SCOPE_AGENT);
                v1 = __hip_atomic_load(src + 1, __ATOMIC_RELAXED, __HIP_MEMORY_SCOPE_AGENT);
                v2 = __hip_atomic_load(src + 2, __ATOMIC_RELAXED, __HIP_MEMORY_SCOPE_AGENT);
                v3 = __hip_atomic_load(src + 3, __ATOMIC_RELAXED, __HIP_MEMORY_SCOPE_AGENT);
                if (((unsigned)(v0 >> 32) == ver) & ((unsigned)(v1 >> 32) == ver) &
                    ((unsigned)(v2 >> 32) == ver) & ((unsigned)(v3 >> 32) == ver))
                    break;
            }
            float4 hv;
            hv.x = __uint_as_float((unsigned)v0);
            hv.y = __uint_as_float((unsigned)v1);
            hv.z = __uint_as_float((unsigned)v2);
            hv.w = __uint_as_float((unsigned)v3);
            ((float4*)h_lds)[tid] = hv;
            __syncthreads();
        }
    }
}

// ---------------------------------------------------------------------------
// K3: four 256x1024 mat-vec projections + bias.  One output per 32-lane group.
// ---------------------------------------------------------------------------
__global__ __launch_bounds__(256) void proj_kernel(
    const float* __restrict__ h_fin, const float* __restrict__ c_fin,
    const float* __restrict__ W_hm, const float* __restrict__ b_hm,
    const float* __restrict__ W_hv, const float* __restrict__ b_hv,
    const float* __restrict__ W_cm, const float* __restrict__ b_cm,
    const float* __restrict__ W_cv, const float* __restrict__ b_cv,
    float* __restrict__ out)
{
    const int tid = threadIdx.x;
    const int g32 = tid >> 5;
    const int j   = tid & 31;
    const int o   = blockIdx.x * 8 + g32;   // 0..1023
    const int mat = o >> 8;
    const int l   = o & 255;

    const float* W;  const float* bias;  const float* vec;
    if      (mat == 0) { W = W_hm; bias = b_hm; vec = h_fin; }
    else if (mat == 1) { W = W_hv; bias = b_hv; vec = h_fin; }
    else if (mat == 2) { W = W_cm; bias = b_cm; vec = c_fin; }
    else               { W = W_cv; bias = b_cv; vec = c_fin; }

    const float* wrow = W + (size_t)l * 1024;
    float acc = 0.0f;
    #pragma unroll
    for (int i = 0; i < 8; ++i) {
        const float4 wv = *(const float4*)(wrow + i * 128 + j * 4);
        const float4 xv = *(const float4*)(vec  + i * 128 + j * 4);
        acc += wv.x * xv.x + wv.y * xv.y + wv.z * xv.z + wv.w * xv.w;
    }
    acc += __shfl_xor(acc, 1);
    acc += __shfl_xor(acc, 2);
    acc += __shfl_xor(acc, 4);
    acc += __shfl_xor(acc, 8);
    acc += __shfl_xor(acc, 16);
    if (j == 0) out[o] = acc + bias[l];
}

// ---------------------------------------------------------------------------
extern "C" void kernel_launch(void* const* d_in, const int* in_sizes, int n_in,
                              void* d_out, int out_size, void* d_ws, size_t ws_size,
                              hipStream_t stream)
{
    const int*   tokens = (const int*)  d_in[0];
    const float* h0     = (const float*)d_in[1];
    const float* c0     = (const float*)d_in[2];
    const float* emb    = (const float*)d_in[3];
    const float* w_ih   = (const float*)d_in[4];
    const float* w_hh   = (const float*)d_in[5];
    const float* b_ih   = (const float*)d_in[6];
    const float* b_hh   = (const float*)d_in[7];
    const float* W_hm   = (const float*)d_in[8];
    const float* b_hm   = (const float*)d_in[9];
    const float* W_hv   = (const float*)d_in[10];
    const float* b_hv   = (const float*)d_in[11];
    const float* W_cm   = (const float*)d_in[12];
    const float* b_cm   = (const float*)d_in[13];
    const float* W_cv   = (const float*)d_in[14];
    const float* b_cv   = (const float*)d_in[15];
    float* out = (float*)d_out;

    char* ws = (char*)d_ws;
    float*              xg    = (float*)ws;            // T*4H fp32 = 64 MB
    size_t              off   = (size_t)T_SEQ * G4 * sizeof(float);
    unsigned long long* h_msg = (unsigned long long*)(ws + off);
    off += 2 * H_DIM * sizeof(unsigned long long);     // 16 KB
    float* h_fin = (float*)(ws + off); off += H_DIM * sizeof(float);
    float* c_fin = (float*)(ws + off); off += H_DIM * sizeof(float);

    // clear stale tags (part of the captured graph => replay-safe)
    hipMemsetAsync(h_msg, 0xFF, 2 * H_DIM * sizeof(unsigned long long), stream);

    xg_gemm<<<dim3(32, 32), 256, 0, stream>>>(tokens, emb, w_ih, b_ih, b_hh, xg);
    lstm_scan<<<NBLK, 256, 0, stream>>>(xg, w_hh, h0, c0, h_msg, h_fin, c_fin);
    proj_kernel<<<128, 256, 0, stream>>>(h_fin, c_fin, W_hm, b_hm, W_hv, b_hv,
                                         W_cm, b_cm, W_cv, b_cv, out);
}

// Round 4
// 12431.170 us; speedup vs baseline: 6.1664x; 1.0471x over previous
//
#include <hip/hip_runtime.h>
#include <math.h>

#define T_SEQ 4096
#define H_DIM 1024
#define G4    4096
#define NBLK  256

// ---------------------------------------------------------------------------
// K1: xg[t][j] = dot(embedding[tokens[t]], w_ih[j]) + b_ih[j] + b_hh[j]
// fp32 GEMM, 128x128 tile, BK=16, 256 threads, 8x8 microtile.
// ---------------------------------------------------------------------------
__global__ __launch_bounds__(256) void xg_gemm(
    const int* __restrict__ tokens, const float* __restrict__ emb,
    const float* __restrict__ w_ih, const float* __restrict__ b_ih,
    const float* __restrict__ b_hh, float* __restrict__ xg)
{
    __shared__ float As[16][128];
    __shared__ float Bs[16][128];
    __shared__ int   tk[128];

    const int tid  = threadIdx.x;
    const int row0 = blockIdx.y * 128;
    const int col0 = blockIdx.x * 128;

    if (tid < 128) tk[tid] = tokens[row0 + tid];
    __syncthreads();

    const int r    = tid >> 1;      // staging row 0..127
    const int half = tid & 1;       // staging k-half
    const int tx   = tid & 15;
    const int ty   = tid >> 4;

    const float* ap_base = emb + (size_t)tk[r] * 1024 + half * 8;
    const float* bp_base = w_ih + (size_t)(col0 + r) * 1024 + half * 8;

    float acc[8][8] = {};

    for (int kc = 0; kc < 1024; kc += 16) {
        const float4 a0 = ((const float4*)(ap_base + kc))[0];
        const float4 a1 = ((const float4*)(ap_base + kc))[1];
        const float4 b0 = ((const float4*)(bp_base + kc))[0];
        const float4 b1 = ((const float4*)(bp_base + kc))[1];
        __syncthreads();   // previous compute finished before overwrite
        const int kb = half * 8;
        As[kb+0][r] = a0.x; As[kb+1][r] = a0.y; As[kb+2][r] = a0.z; As[kb+3][r] = a0.w;
        As[kb+4][r] = a1.x; As[kb+5][r] = a1.y; As[kb+6][r] = a1.z; As[kb+7][r] = a1.w;
        Bs[kb+0][r] = b0.x; Bs[kb+1][r] = b0.y; Bs[kb+2][r] = b0.z; Bs[kb+3][r] = b0.w;
        Bs[kb+4][r] = b1.x; Bs[kb+5][r] = b1.y; Bs[kb+6][r] = b1.z; Bs[kb+7][r] = b1.w;
        __syncthreads();
        #pragma unroll
        for (int k = 0; k < 16; ++k) {
            const float4 a0v = *(const float4*)&As[k][ty*8];
            const float4 a1v = *(const float4*)&As[k][ty*8+4];
            const float4 b0v = *(const float4*)&Bs[k][tx*8];
            const float4 b1v = *(const float4*)&Bs[k][tx*8+4];
            const float aa[8] = {a0v.x,a0v.y,a0v.z,a0v.w,a1v.x,a1v.y,a1v.z,a1v.w};
            const float bb[8] = {b0v.x,b0v.y,b0v.z,b0v.w,b1v.x,b1v.y,b1v.z,b1v.w};
            #pragma unroll
            for (int ii = 0; ii < 8; ++ii)
                #pragma unroll
                for (int jj = 0; jj < 8; ++jj)
                    acc[ii][jj] = fmaf(aa[ii], bb[jj], acc[ii][jj]);
        }
    }

    const int ccol = col0 + tx * 8;
    float bs[8];
    #pragma unroll
    for (int jj = 0; jj < 8; ++jj) bs[jj] = b_ih[ccol + jj] + b_hh[ccol + jj];
    #pragma unroll
    for (int ii = 0; ii < 8; ++ii) {
        float* orow = xg + (size_t)(row0 + ty*8 + ii) * G4 + ccol;
        float4 o0, o1;
        o0.x = acc[ii][0] + bs[0]; o0.y = acc[ii][1] + bs[1];
        o0.z = acc[ii][2] + bs[2]; o0.w = acc[ii][3] + bs[3];
        o1.x = acc[ii][4] + bs[4]; o1.y = acc[ii][5] + bs[5];
        o1.z = acc[ii][6] + bs[6]; o1.w = acc[ii][7] + bs[7];
        ((float4*)orow)[0] = o0;
        ((float4*)orow)[1] = o1;
    }
}

// ---------------------------------------------------------------------------
// K2: persistent LSTM scan.  256 blocks x 256 threads; block b owns h-lanes
// {4b..4b+3} (16 gate rows).  w_hh slice held in VGPRs via inline-asm
// global_load_dwordx4 (rounds 2/3 showed source-level loads get remat'd into
// the loop: VGPR=64, FETCH 660MB; a volatile-asm def has no remat source).
// Cross-block h exchange: 8-byte relaxed agent-scope atomics carrying
// {tag = version, float bits}; no fences, no counters.  2-slot ring safe:
// max inter-block skew is 1 step.
// ---------------------------------------------------------------------------
__device__ __forceinline__ float fsigmoid_(float x) {
    return 1.0f / (1.0f + __expf(-x));          // exp->inf => 0, no NaN
}
__device__ __forceinline__ float ftanh_(float x) {
    x = fminf(fmaxf(x, -10.0f), 10.0f);         // avoid inf/inf
    const float e = __expf(2.0f * x);
    return (e - 1.0f) / (e + 1.0f);
}

__global__ __launch_bounds__(256, 1) void lstm_scan(
    const float* __restrict__ xg, const float* __restrict__ w_hh,
    const float* __restrict__ h0, const float* __restrict__ c0,
    unsigned long long* h_msg,           // [2][1024] {tag,bits}
    float* __restrict__ h_fin, float* __restrict__ c_fin)
{
    __shared__ float h_lds[H_DIM];
    __shared__ float dot_lds[16];

    const int tid  = threadIdx.x;
    const int b    = blockIdx.x;
    const int w    = tid >> 6;       // wave index = gate index (i,f,g,o)
    const int lane = tid & 63;
    const int s    = lane >> 2;      // k-slice 0..15 (64 floats each)
    const int m    = lane & 3;       // which of the block's 4 h-lanes
    const int row  = w * 1024 + 4 * b + m;

    // --- resident weights: volatile-asm loads => defs the compiler cannot
    // rematerialize; values stay in VGPRs for the whole kernel.
    // chunk order rotated by s so paired h_lds reads are conflict-light.
    float4 wf[16];
    {
        const float* wp = w_hh + (size_t)row * 1024 + 64 * s;
        #pragma unroll
        for (int i = 0; i < 16; ++i) {
            const float* a = wp + 4 * ((i + s) & 15);
            asm volatile("global_load_dwordx4 %0, %1, off"
                         : "=v"(wf[i]) : "v"(a) : "memory");
        }
        asm volatile("s_waitcnt vmcnt(0)" ::: "memory");
        __builtin_amdgcn_sched_barrier(0);   // rule: no hoisting past waitcnt
    }

    float c_reg = 0.0f;
    if (tid < 4) c_reg = c0[4 * b + tid];

    // version 0 of h comes straight from h0
    ((float4*)h_lds)[tid] = ((const float4*)h0)[tid];
    __syncthreads();

    // prefetch xg for t=0
    float xc0 = 0.f, xc1 = 0.f, xc2 = 0.f, xc3 = 0.f;
    if (tid < 4) {
        const float* p = xg + 4 * b + tid;
        xc0 = p[0]; xc1 = p[1024]; xc2 = p[2048]; xc3 = p[3072];
    }

    for (int t = 0; t < T_SEQ; ++t) {
        // issue next step's xg load now; consumed next iteration
        float xn0 = 0.f, xn1 = 0.f, xn2 = 0.f, xn3 = 0.f;
        if ((tid < 4) & (t < T_SEQ - 1)) {
            const float* p = xg + (size_t)(t + 1) * G4 + 4 * b + tid;
            xn0 = p[0]; xn1 = p[1024]; xn2 = p[2048]; xn3 = p[3072];
        }

        // 64-MAC partial dot: resident weights x broadcast h (LDS)
        float acc = 0.0f;
        const float4* h4 = (const float4*)h_lds;
        #pragma unroll
        for (int i = 0; i < 16; ++i) {
            const int c = (i + s) & 15;
            const float4 x = h4[16 * s + c];
            acc = fmaf(wf[i].x, x.x, acc);
            acc = fmaf(wf[i].y, x.y, acc);
            acc = fmaf(wf[i].z, x.z, acc);
            acc = fmaf(wf[i].w, x.w, acc);
        }
        acc += __shfl_xor(acc, 4);
        acc += __shfl_xor(acc, 8);
        acc += __shfl_xor(acc, 16);
        acc += __shfl_xor(acc, 32);
        if (lane < 4) dot_lds[w * 4 + lane] = acc;
        __syncthreads();

        // pointwise update + publish (4 threads; other waves fall through to
        // the poll below and spin concurrently)
        if (tid < 4) {
            const float gi = xc0 + dot_lds[0  + tid];
            const float gf = xc1 + dot_lds[4  + tid];
            const float gg = xc2 + dot_lds[8  + tid];
            const float go = xc3 + dot_lds[12 + tid];
            const float ii = fsigmoid_(gi);
            const float ff = fsigmoid_(gf);
            const float gt = ftanh_(gg);
            const float oo = fsigmoid_(go);
            c_reg = ff * c_reg + ii * gt;
            const float hn = oo * ftanh_(c_reg);
            const unsigned long long msg =
                ((unsigned long long)(unsigned)(t + 1) << 32) | __float_as_uint(hn);
            __hip_atomic_store(&h_msg[(size_t)((t + 1) & 1) * H_DIM + 4 * b + tid],
                               msg, __ATOMIC_RELAXED, __HIP_MEMORY_SCOPE_AGENT);
            if (t == T_SEQ - 1) {
                h_fin[4 * b + tid] = hn;
                c_fin[4 * b + tid] = c_reg;
            }
        }
        xc0 = xn0; xc1 = xn1; xc2 = xn2; xc3 = xn3;

        // gather h version t+1 (each thread owns 4 consecutive h values)
        if (t < T_SEQ - 1) {
            const unsigned ver = (unsigned)(t + 1);
            const unsigned long long* src =
                h_msg + (size_t)(ver & 1) * H_DIM + 4 * tid;
            unsigned long long v0, v1, v2, v3;
            for (;;) {
                v0 = __hip_atomic_load(src + 0, __ATOMIC_RELAXED, __HIP_MEMORY_SCOPE_AGENT);
                v1 = __hip_atomic_load(src + 1, __ATOMIC_RELAXED, __HIP_MEMORY_SCOPE_AGENT);
                v2 = __hip_atomic_load(src + 2, __ATOMIC_RELAXED, __HIP_MEMORY_SCOPE_AGENT);
                v3 = __hip_atomic_load(src + 3, __ATOMIC_RELAXED, __HIP_MEMORY_SCOPE_AGENT);
                if (((unsigned)(v0 >> 32) == ver) & ((unsigned)(v1 >> 32) == ver) &
                    ((unsigned)(v2 >> 32) == ver) & ((unsigned)(v3 >> 32) == ver))
                    break;
            }
            float4 hv;
            hv.x = __uint_as_float((unsigned)v0);
            hv.y = __uint_as_float((unsigned)v1);
            hv.z = __uint_as_float((unsigned)v2);
            hv.w = __uint_as_float((unsigned)v3);
            ((float4*)h_lds)[tid] = hv;
            __syncthreads();
        }
    }
}

// ---------------------------------------------------------------------------
// K3: four 256x1024 mat-vec projections + bias.  One output per 32-lane group.
// ---------------------------------------------------------------------------
__global__ __launch_bounds__(256) void proj_kernel(
    const float* __restrict__ h_fin, const float* __restrict__ c_fin,
    const float* __restrict__ W_hm, const float* __restrict__ b_hm,
    const float* __restrict__ W_hv, const float* __restrict__ b_hv,
    const float* __restrict__ W_cm, const float* __restrict__ b_cm,
    const float* __restrict__ W_cv, const float* __restrict__ b_cv,
    float* __restrict__ out)
{
    const int tid = threadIdx.x;
    const int g32 = tid >> 5;
    const int j   = tid & 31;
    const int o   = blockIdx.x * 8 + g32;   // 0..1023
    const int mat = o >> 8;
    const int l   = o & 255;

    const float* W;  const float* bias;  const float* vec;
    if      (mat == 0) { W = W_hm; bias = b_hm; vec = h_fin; }
    else if (mat == 1) { W = W_hv; bias = b_hv; vec = h_fin; }
    else if (mat == 2) { W = W_cm; bias = b_cm; vec = c_fin; }
    else               { W = W_cv; bias = b_cv; vec = c_fin; }

    const float* wrow = W + (size_t)l * 1024;
    float acc = 0.0f;
    #pragma unroll
    for (int i = 0; i < 8; ++i) {
        const float4 wv = *(const float4*)(wrow + i * 128 + j * 4);
        const float4 xv = *(const float4*)(vec  + i * 128 + j * 4);
        acc += wv.x * xv.x + wv.y * xv.y + wv.z * xv.z + wv.w * xv.w;
    }
    acc += __shfl_xor(acc, 1);
    acc += __shfl_xor(acc, 2);
    acc += __shfl_xor(acc, 4);
    acc += __shfl_xor(acc, 8);
    acc += __shfl_xor(acc, 16);
    if (j == 0) out[o] = acc + bias[l];
}

// ---------------------------------------------------------------------------
extern "C" void kernel_launch(void* const* d_in, const int* in_sizes, int n_in,
                              void* d_out, int out_size, void* d_ws, size_t ws_size,
                              hipStream_t stream)
{
    const int*   tokens = (const int*)  d_in[0];
    const float* h0     = (const float*)d_in[1];
    const float* c0     = (const float*)d_in[2];
    const float* emb    = (const float*)d_in[3];
    const float* w_ih   = (const float*)d_in[4];
    const float* w_hh   = (const float*)d_in[5];
    const float* b_ih   = (const float*)d_in[6];
    const float* b_hh   = (const float*)d_in[7];
    const float* W_hm   = (const float*)d_in[8];
    const float* b_hm   = (const float*)d_in[9];
    const float* W_hv   = (const float*)d_in[10];
    const float* b_hv   = (const float*)d_in[11];
    const float* W_cm   = (const float*)d_in[12];
    const float* b_cm   = (const float*)d_in[13];
    const float* W_cv   = (const float*)d_in[14];
    const float* b_cv   = (const float*)d_in[15];
    float* out = (float*)d_out;

    char* ws = (char*)d_ws;
    float*              xg    = (float*)ws;            // T*4H fp32 = 64 MB
    size_t              off   = (size_t)T_SEQ * G4 * sizeof(float);
    unsigned long long* h_msg = (unsigned long long*)(ws + off);
    off += 2 * H_DIM * sizeof(unsigned long long);     // 16 KB
    float* h_fin = (float*)(ws + off); off += H_DIM * sizeof(float);
    float* c_fin = (float*)(ws + off); off += H_DIM * sizeof(float);

    // clear stale tags (part of the captured graph => replay-safe)
    hipMemsetAsync(h_msg, 0xFF, 2 * H_DIM * sizeof(unsigned long long), stream);

    xg_gemm<<<dim3(32, 32), 256, 0, stream>>>(tokens, emb, w_ih, b_ih, b_hh, xg);
    lstm_scan<<<NBLK, 256, 0, stream>>>(xg, w_hh, h0, c0, h_msg, h_fin, c_fin);
    proj_kernel<<<128, 256, 0, stream>>>(h_fin, c_fin, W_hm, b_hm, W_hv, b_hv,
                                         W_cm, b_cm, W_cv, b_cv, out);
}

// Round 5
// 7946.744 us; speedup vs baseline: 9.6461x; 1.5643x over previous
//
#include <hip/hip_runtime.h>
#include <math.h>

#define T_SEQ 4096
#define H_DIM 1024
#define G4    4096
#define NBLK  64      // scan blocks; each owns 16 h-lanes (64 gate rows)
#define NTHR  512

// ---------------------------------------------------------------------------
// K1: xg[t][j] = dot(embedding[tokens[t]], w_ih[j]) + b_ih[j] + b_hh[j]
// fp32 GEMM, 128x128 tile, BK=16, 256 threads, 8x8 microtile.
// ---------------------------------------------------------------------------
__global__ __launch_bounds__(256) void xg_gemm(
    const int* __restrict__ tokens, const float* __restrict__ emb,
    const float* __restrict__ w_ih, const float* __restrict__ b_ih,
    const float* __restrict__ b_hh, float* __restrict__ xg)
{
    __shared__ float As[16][128];
    __shared__ float Bs[16][128];
    __shared__ int   tk[128];

    const int tid  = threadIdx.x;
    const int row0 = blockIdx.y * 128;
    const int col0 = blockIdx.x * 128;

    if (tid < 128) tk[tid] = tokens[row0 + tid];
    __syncthreads();

    const int r    = tid >> 1;
    const int half = tid & 1;
    const int tx   = tid & 15;
    const int ty   = tid >> 4;

    const float* ap_base = emb + (size_t)tk[r] * 1024 + half * 8;
    const float* bp_base = w_ih + (size_t)(col0 + r) * 1024 + half * 8;

    float acc[8][8] = {};

    for (int kc = 0; kc < 1024; kc += 16) {
        const float4 a0 = ((const float4*)(ap_base + kc))[0];
        const float4 a1 = ((const float4*)(ap_base + kc))[1];
        const float4 b0 = ((const float4*)(bp_base + kc))[0];
        const float4 b1 = ((const float4*)(bp_base + kc))[1];
        __syncthreads();
        const int kb = half * 8;
        As[kb+0][r] = a0.x; As[kb+1][r] = a0.y; As[kb+2][r] = a0.z; As[kb+3][r] = a0.w;
        As[kb+4][r] = a1.x; As[kb+5][r] = a1.y; As[kb+6][r] = a1.z; As[kb+7][r] = a1.w;
        Bs[kb+0][r] = b0.x; Bs[kb+1][r] = b0.y; Bs[kb+2][r] = b0.z; Bs[kb+3][r] = b0.w;
        Bs[kb+4][r] = b1.x; Bs[kb+5][r] = b1.y; Bs[kb+6][r] = b1.z; Bs[kb+7][r] = b1.w;
        __syncthreads();
        #pragma unroll
        for (int k = 0; k < 16; ++k) {
            const float4 a0v = *(const float4*)&As[k][ty*8];
            const float4 a1v = *(const float4*)&As[k][ty*8+4];
            const float4 b0v = *(const float4*)&Bs[k][tx*8];
            const float4 b1v = *(const float4*)&Bs[k][tx*8+4];
            const float aa[8] = {a0v.x,a0v.y,a0v.z,a0v.w,a1v.x,a1v.y,a1v.z,a1v.w};
            const float bb[8] = {b0v.x,b0v.y,b0v.z,b0v.w,b1v.x,b1v.y,b1v.z,b1v.w};
            #pragma unroll
            for (int ii = 0; ii < 8; ++ii)
                #pragma unroll
                for (int jj = 0; jj < 8; ++jj)
                    acc[ii][jj] = fmaf(aa[ii], bb[jj], acc[ii][jj]);
        }
    }

    const int ccol = col0 + tx * 8;
    float bs[8];
    #pragma unroll
    for (int jj = 0; jj < 8; ++jj) bs[jj] = b_ih[ccol + jj] + b_hh[ccol + jj];
    #pragma unroll
    for (int ii = 0; ii < 8; ++ii) {
        float* orow = xg + (size_t)(row0 + ty*8 + ii) * G4 + ccol;
        float4 o0, o1;
        o0.x = acc[ii][0] + bs[0]; o0.y = acc[ii][1] + bs[1];
        o0.z = acc[ii][2] + bs[2]; o0.w = acc[ii][3] + bs[3];
        o1.x = acc[ii][4] + bs[4]; o1.y = acc[ii][5] + bs[5];
        o1.z = acc[ii][6] + bs[6]; o1.w = acc[ii][7] + bs[7];
        ((float4*)orow)[0] = o0;
        ((float4*)orow)[1] = o1;
    }
}

// ---------------------------------------------------------------------------
// K2: persistent LSTM scan.  64 blocks x 512 threads; block b owns h-lanes
// {16b..16b+15} (64 gate rows).  Weights stream from per-XCD L2 (2 MB
// working set per XCD; rounds 2-4 proved VGPR residency is unattainable AND
// irrelevant — L2 serves them off the critical path).  Critical path is the
// cross-block exchange: 64 participants, each thread polls only its OWN two
// 8-byte tagged messages {ver,bits} (relaxed agent-scope atomics, no fences).
// 2-slot ring, max skew 1 step.
// ---------------------------------------------------------------------------
__device__ __forceinline__ float fsigmoid_(float x) {
    return 1.0f / (1.0f + __expf(-x));
}
__device__ __forceinline__ float ftanh_(float x) {
    x = fminf(fmaxf(x, -10.0f), 10.0f);
    const float e = __expf(2.0f * x);
    return (e - 1.0f) / (e + 1.0f);
}

__global__ __launch_bounds__(NTHR, 2) void lstm_scan(
    const float* __restrict__ xg, const float* __restrict__ w_hh,
    const float* __restrict__ h0, const float* __restrict__ c0,
    unsigned long long* h_msg,           // [2][1024] {tag,bits}
    float* __restrict__ h_fin, float* __restrict__ c_fin)
{
    __shared__ float h_lds[H_DIM];       // linear h, read rotated (+j) => no conflicts
    __shared__ float dot_lds[64];
    __shared__ float xg_lds[64];

    const int tid = threadIdx.x;
    const int b   = blockIdx.x;
    const int j   = tid & 7;             // k-slice: 128 floats = 32 float4
    const int r   = tid >> 3;            // gate-row within block: 0..63
    const int g   = r >> 4;              // gate 0..3
    const int m   = r & 15;              // h-lane within block
    const int row = g * 1024 + 16 * b + m;

    const float4* wbase = (const float4*)(w_hh + (size_t)row * 1024) + 32 * j;
    const float4* h4    = (const float4*)h_lds + 32 * j;

    float c_reg = 0.0f;
    if (tid < 16) c_reg = c0[16 * b + tid];

    // h version 0 from h0
    ((float2*)h_lds)[tid] = ((const float2*)h0)[tid];

    // prefetch xg for t=0 (thread tid<64 owns gate g2=tid>>4, lane m2=tid&15)
    float xc = 0.0f;
    if (tid < 64)
        xc = xg[(size_t)(tid >> 4) * 1024 + 16 * b + (tid & 15)];
    __syncthreads();

    for (int t = 0; t < T_SEQ; ++t) {
        // stage this step's xg into LDS; issue next step's prefetch
        if (tid < 64) {
            xg_lds[tid] = xc;
            if (t < T_SEQ - 1)
                xc = xg[(size_t)(t + 1) * G4 + (tid >> 4) * 1024 + 16 * b + (tid & 15)];
        }

        // 128-MAC partial dot: w (L2 stream) x h (LDS, +j rotated -> 8 distinct
        // b128 addrs x 8-lane broadcast per instruction = conflict-free)
        float acc = 0.0f;
        #pragma unroll
        for (int i = 0; i < 32; ++i) {
            const int idx = (i + j) & 31;
            const float4 wv = wbase[idx];
            const float4 hv = h4[idx];
            acc = fmaf(wv.x, hv.x, acc);
            acc = fmaf(wv.y, hv.y, acc);
            acc = fmaf(wv.z, hv.z, acc);
            acc = fmaf(wv.w, hv.w, acc);
        }
        acc += __shfl_xor(acc, 1);
        acc += __shfl_xor(acc, 2);
        acc += __shfl_xor(acc, 4);
        if ((tid & 7) == 0) dot_lds[r] = acc;
        __syncthreads();

        // pointwise update + publish (16 threads; rest proceed to their polls)
        if (tid < 16) {
            const float gi = xg_lds[tid]      + dot_lds[tid];
            const float gf = xg_lds[16 + tid] + dot_lds[16 + tid];
            const float gg = xg_lds[32 + tid] + dot_lds[32 + tid];
            const float go = xg_lds[48 + tid] + dot_lds[48 + tid];
            const float ii = fsigmoid_(gi);
            const float ff = fsigmoid_(gf);
            const float gt = ftanh_(gg);
            const float oo = fsigmoid_(go);
            c_reg = ff * c_reg + ii * gt;
            const float hn = oo * ftanh_(c_reg);
            const unsigned long long msg =
                ((unsigned long long)(unsigned)(t + 1) << 32) | __float_as_uint(hn);
            __hip_atomic_store(&h_msg[(size_t)((t + 1) & 1) * H_DIM + 16 * b + tid],
                               msg, __ATOMIC_RELAXED, __HIP_MEMORY_SCOPE_AGENT);
            if (t == T_SEQ - 1) {
                h_fin[16 * b + tid] = hn;
                c_fin[16 * b + tid] = c_reg;
            }
        }

        // gather h version t+1: each thread polls only its own 2 messages
        // (wave reads 1 KB contiguous -> coalesced)
        if (t < T_SEQ - 1) {
            const unsigned ver = (unsigned)(t + 1);
            const unsigned long long* src =
                h_msg + (size_t)(ver & 1) * H_DIM + 2 * tid;
            unsigned long long v0, v1;
            for (;;) {
                v0 = __hip_atomic_load(src + 0, __ATOMIC_RELAXED, __HIP_MEMORY_SCOPE_AGENT);
                v1 = __hip_atomic_load(src + 1, __ATOMIC_RELAXED, __HIP_MEMORY_SCOPE_AGENT);
                if (((unsigned)(v0 >> 32) == ver) & ((unsigned)(v1 >> 32) == ver))
                    break;
            }
            float2 hv;
            hv.x = __uint_as_float((unsigned)v0);
            hv.y = __uint_as_float((unsigned)v1);
            ((float2*)h_lds)[tid] = hv;
            __syncthreads();
        }
    }
}

// ---------------------------------------------------------------------------
// K3: four 256x1024 mat-vec projections + bias.  One output per 32-lane group.
// ---------------------------------------------------------------------------
__global__ __launch_bounds__(256) void proj_kernel(
    const float* __restrict__ h_fin, const float* __restrict__ c_fin,
    const float* __restrict__ W_hm, const float* __restrict__ b_hm,
    const float* __restrict__ W_hv, const float* __restrict__ b_hv,
    const float* __restrict__ W_cm, const float* __restrict__ b_cm,
    const float* __restrict__ W_cv, const float* __restrict__ b_cv,
    float* __restrict__ out)
{
    const int tid = threadIdx.x;
    const int g32 = tid >> 5;
    const int j   = tid & 31;
    const int o   = blockIdx.x * 8 + g32;   // 0..1023
    const int mat = o >> 8;
    const int l   = o & 255;

    const float* W;  const float* bias;  const float* vec;
    if      (mat == 0) { W = W_hm; bias = b_hm; vec = h_fin; }
    else if (mat == 1) { W = W_hv; bias = b_hv; vec = h_fin; }
    else if (mat == 2) { W = W_cm; bias = b_cm; vec = c_fin; }
    else               { W = W_cv; bias = b_cv; vec = c_fin; }

    const float* wrow = W + (size_t)l * 1024;
    float acc = 0.0f;
    #pragma unroll
    for (int i = 0; i < 8; ++i) {
        const float4 wv = *(const float4*)(wrow + i * 128 + j * 4);
        const float4 xv = *(const float4*)(vec  + i * 128 + j * 4);
        acc += wv.x * xv.x + wv.y * xv.y + wv.z * xv.z + wv.w * xv.w;
    }
    acc += __shfl_xor(acc, 1);
    acc += __shfl_xor(acc, 2);
    acc += __shfl_xor(acc, 4);
    acc += __shfl_xor(acc, 8);
    acc += __shfl_xor(acc, 16);
    if (j == 0) out[o] = acc + bias[l];
}

// ---------------------------------------------------------------------------
extern "C" void kernel_launch(void* const* d_in, const int* in_sizes, int n_in,
                              void* d_out, int out_size, void* d_ws, size_t ws_size,
                              hipStream_t stream)
{
    const int*   tokens = (const int*)  d_in[0];
    const float* h0     = (const float*)d_in[1];
    const float* c0     = (const float*)d_in[2];
    const float* emb    = (const float*)d_in[3];
    const float* w_ih   = (const float*)d_in[4];
    const float* w_hh   = (const float*)d_in[5];
    const float* b_ih   = (const float*)d_in[6];
    const float* b_hh   = (const float*)d_in[7];
    const float* W_hm   = (const float*)d_in[8];
    const float* b_hm   = (const float*)d_in[9];
    const float* W_hv   = (const float*)d_in[10];
    const float* b_hv   = (const float*)d_in[11];
    const float* W_cm   = (const float*)d_in[12];
    const float* b_cm   = (const float*)d_in[13];
    const float* W_cv   = (const float*)d_in[14];
    const float* b_cv   = (const float*)d_in[15];
    float* out = (float*)d_out;

    char* ws = (char*)d_ws;
    float*              xg    = (float*)ws;            // T*4H fp32 = 64 MB
    size_t              off   = (size_t)T_SEQ * G4 * sizeof(float);
    unsigned long long* h_msg = (unsigned long long*)(ws + off);
    off += 2 * H_DIM * sizeof(unsigned long long);     // 16 KB
    float* h_fin = (float*)(ws + off); off += H_DIM * sizeof(float);
    float* c_fin = (float*)(ws + off); off += H_DIM * sizeof(float);

    // clear stale tags (part of the captured graph => replay-safe)
    hipMemsetAsync(h_msg, 0xFF, 2 * H_DIM * sizeof(unsigned long long), stream);

    xg_gemm<<<dim3(32, 32), 256, 0, stream>>>(tokens, emb, w_ih, b_ih, b_hh, xg);
    lstm_scan<<<NBLK, NTHR, 0, stream>>>(xg, w_hh, h0, c0, h_msg, h_fin, c_fin);
    proj_kernel<<<128, 256, 0, stream>>>(h_fin, c_fin, W_hm, b_hm, W_hv, b_hv,
                                         W_cm, b_cm, W_cv, b_cv, out);
}